// Round 12
// baseline (108.673 us; speedup 1.0000x reference)
//
#include <hip/hip_runtime.h>

#define LN 4096
#define DN 150
#define NT 10          // d padded to 10 x 16 tiles

// legacy (TR=1) geometry
#define KSPLIT 4
#define KQ 1024        // k per block
#define NSS 4          // super-steps of 256 k

// h_out (k_gemm_a) geometry
#define KS0 8
#define KQ0 (LN / KS0)     // 512 k per block
#define NS0 (KQ0 / 64)     // 8 slices of 64 k

typedef __attribute__((ext_vector_type(8))) short bf16x8;
typedef __attribute__((ext_vector_type(4))) float f32x4;
typedef __attribute__((address_space(1))) const unsigned char gl_u8;
typedef __attribute__((address_space(3))) unsigned char lds_u8;

// round-to-nearest-even fp32 -> bf16 (finite inputs only)
__device__ __forceinline__ unsigned short f2bf(float f) {
    unsigned int u = __builtin_bit_cast(unsigned int, f);
    u = (u + 0x7FFFu + ((u >> 16) & 1u)) >> 16;
    return (unsigned short)u;
}

__global__ __launch_bounds__(256) void k_zero(f32x4* __restrict__ p, int n4) {
    int i = blockIdx.x * 256 + threadIdx.x;
    if (i < n4) p[i] = (f32x4){0.f, 0.f, 0.f, 0.f};
}

// h [4096][150] f32  ->  Ht [160][4096] bf16 (rows 150..159 zero)
__global__ __launch_bounds__(256) void k_transpose(const float* __restrict__ h,
                                                   unsigned short* __restrict__ Ht) {
    __shared__ float S[64][33];
    const int i0 = blockIdx.x * 64;
    const int d0 = blockIdx.y * 32;
    const int tid = threadIdx.x;
    for (int t = tid; t < 64 * 32; t += 256) {
        int ii = t >> 5, dd = t & 31;
        int d = d0 + dd;
        S[ii][dd] = (d < DN) ? h[(size_t)(i0 + ii) * DN + d] : 0.0f;
    }
    __syncthreads();
    for (int t = tid; t < 32 * 64; t += 256) {
        int dd = t >> 6, ii = t & 63;
        Ht[(size_t)(d0 + dd) * LN + i0 + ii] = f2bf(S[ii][dd]);
    }
}

// out h_in = sum of 4 pIn partials; out h_out = sum of 8 pOut partials.
__global__ __launch_bounds__(256) void k_reduce(const float* __restrict__ pIn,
                                                const float* __restrict__ pOut,
                                                float* __restrict__ out, int n4) {
    int i = blockIdx.x * 256 + threadIdx.x;
    if (i >= n4) return;
    const f32x4* a = reinterpret_cast<const f32x4*>(pIn);
    const f32x4* b = reinterpret_cast<const f32x4*>(pOut);
    f32x4 s0 = a[i], s1 = b[i];
    #pragma unroll
    for (int k = 1; k < KSPLIT; ++k) s0 += a[(size_t)k * n4 + i];
    #pragma unroll
    for (int k = 1; k < KS0; ++k)    s1 += b[(size_t)k * n4 + i];
    reinterpret_cast<f32x4*>(out)[i] = s0;             // h_in
    reinterpret_cast<f32x4*>(out)[n4 + i] = s1;        // h_out
}

// ---------------- h_out gemm: global_load_lds staging of raw fp32 adj ----------------
// part[by][m0+row][d] = sum_{k in block range} bf16(adj[m][k][0]+adj[m][k][1]) * Ht[d][k]
// 4 waves; wave w owns rows w*16..w*16+15 over the full 64-k slice (2 MFMA sub-steps).
// LDS slice: [64 rows][512B]; 16B LDS chunk c of row r holds global chunk c^(r&7)
// (linear LDS dest + pre-swizzled per-lane global source; reader XORs the same).
__global__ __launch_bounds__(256, 2) void k_gemm_a(const float* __restrict__ adj,
                                                   const unsigned short* __restrict__ Ht,
                                                   float* __restrict__ part) {
    __shared__ char At[2][32768];   // 2 x 32KB double buffer
    const int tid  = threadIdx.x;
    const int lane = tid & 63;
    const int w    = tid >> 6;   // wave = m-subtile (16 rows)
    const int r16  = lane & 15;  // A row / B col / C col within 16-tile
    const int g    = lane >> 4;  // k-group
    const int m0 = blockIdx.x * 64;
    const int kq = blockIdx.y * KQ0;

    f32x4 acc[NT];
    #pragma unroll
    for (int n = 0; n < NT; ++n) acc[n] = (f32x4){0.f, 0.f, 0.f, 0.f};

    auto stage = [&](int buf, int ss) {
        const int kb = kq + ss * 64;
        #pragma unroll
        for (int t = 0; t < 8; ++t) {
            const int r0  = w * 16 + t * 2;          // wave-uniform
            const int row = r0 + (lane >> 5);        // 2 rows per 1KB wave-load
            const float* src = adj + ((size_t)(m0 + row) * LN + kb) * 2
                                   + (((lane & 31) ^ (row & 7)) << 2);
            __builtin_amdgcn_global_load_lds((gl_u8*)src,
                                             (lds_u8*)(&At[buf][r0 * 512]), 16, 0, 0);
        }
    };

    const int rA  = w * 16 + r16;    // this lane's A row in the 64-row tile
    const int swz = rA & 7;

    stage(0, 0);
    __syncthreads();                 // drain: buf0 ready
    for (int ss = 0; ss < NS0; ++ss) {
        const int buf = ss & 1;
        if (ss + 1 < NS0) stage(buf ^ 1, ss + 1);   // issue early; flies during compute
        #pragma unroll
        for (int sh = 0; sh < 2; ++sh) {            // two 32-k MFMA sub-steps per slice
            const int k = kq + ss * 64 + sh * 32 + g * 8;
            bf16x8 B[NT];
            #pragma unroll
            for (int n = 0; n < NT; ++n)
                B[n] = *reinterpret_cast<const bf16x8*>(Ht + (size_t)(n * 16 + r16) * LN + k);
            f32x4 v[4];
            #pragma unroll
            for (int j = 0; j < 4; ++j)
                v[j] = *reinterpret_cast<const f32x4*>(
                    &At[buf][rA * 512 + (((sh * 16 + g * 4 + j) ^ swz) << 4)]);
            bf16x8 a;
            #pragma unroll
            for (int j = 0; j < 4; ++j) {
                a[2 * j]     = (short)f2bf(v[j].x + v[j].y);
                a[2 * j + 1] = (short)f2bf(v[j].z + v[j].w);
            }
            #pragma unroll
            for (int n = 0; n < NT; ++n)
                acc[n] = __builtin_amdgcn_mfma_f32_16x16x32_bf16(a, B[n], acc[n], 0, 0, 0);
        }
        __syncthreads();             // readers done with buf; buf^1 staging drained
    }

    // direct partial store — each wave owns its 16 rows outright (no cross-wave reduce)
    float* dst = part + (size_t)blockIdx.y * (LN * DN);
    #pragma unroll
    for (int n = 0; n < NT; ++n) {
        #pragma unroll
        for (int q = 0; q < 4; ++q) {
            int row = w * 16 + g * 4 + q;   // C: col=lane&15, row=(lane>>4)*4+q
            int col = n * 16 + r16;
            if (col < DN) dst[(size_t)(m0 + row) * DN + col] = acc[n][q];
        }
    }
}

// ---------------- legacy reg-staged gemm (TR=1 main path + fallback) ----------------
template <int TR>
__global__ __launch_bounds__(256, 2) void k_gemm(const float* __restrict__ adj,
                                                 const unsigned short* __restrict__ Ht,
                                                 float* __restrict__ part,
                                                 float* __restrict__ out) {
    __shared__ unsigned short At[2][32 * 256];
    __shared__ float red[32][160];
    const int tid  = threadIdx.x;
    const int lane = tid & 63;
    const int wave = tid >> 6;
    const int r16  = lane & 15;
    const int g    = lane >> 4;
    const int m0 = blockIdx.x * 32;
    const int kq = blockIdx.y * KQ;

    f32x4 acc[2][NT];
    #pragma unroll
    for (int mt = 0; mt < 2; ++mt)
        #pragma unroll
        for (int n = 0; n < NT; ++n) acc[mt][n] = (f32x4){0.f, 0.f, 0.f, 0.f};

    f32x4 sv[16];

    auto stage_load = [&](int ss) {
        if (TR == 0) {
            const int row = tid >> 7;
            const int kk  = tid & 127;
            #pragma unroll
            for (int rr = 0; rr < 16; ++rr) {
                int rowr = rr * 2 + row;
                sv[rr] = *reinterpret_cast<const f32x4*>(
                    adj + ((size_t)(m0 + rowr) * LN + kq + ss * 256 + 2 * kk) * 2);
            }
        } else {
            const int iof = tid >> 4;
            const int jp  = tid & 15;
            #pragma unroll
            for (int rr = 0; rr < 16; ++rr) {
                int il = rr * 16 + iof;
                sv[rr] = *reinterpret_cast<const f32x4*>(
                    adj + ((size_t)(kq + ss * 256 + il) * LN + m0 + jp * 2) * 2);
            }
        }
    };
    auto stage_write = [&](int buf) {
        if (TR == 0) {
            const int row = tid >> 7;
            const int kk  = tid & 127;
            #pragma unroll
            for (int rr = 0; rr < 16; ++rr) {
                int rowr = rr * 2 + row;
                unsigned int u = (unsigned int)f2bf(sv[rr].x + sv[rr].y) |
                                 ((unsigned int)f2bf(sv[rr].z + sv[rr].w) << 16);
                *reinterpret_cast<unsigned int*>(
                    &At[buf][rowr * 256 + ((2 * kk) ^ ((rowr & 15) << 3))]) = u;
            }
        } else {
            const int iof = tid >> 4;
            const int jA  = (tid & 15) * 2, jB = jA + 1;
            #pragma unroll
            for (int rr = 0; rr < 16; ++rr) {
                int k = rr * 16 + iof;
                At[buf][jA * 256 + (k ^ ((jA & 15) << 3))] = f2bf(sv[rr].x + sv[rr].y);
                At[buf][jB * 256 + (k ^ ((jB & 15) << 3))] = f2bf(sv[rr].z + sv[rr].w);
            }
        }
    };
    auto frag = [&](int buf, int mt, int s) {
        int row  = mt * 16 + r16;
        int kloc = wave * 64 + s * 32 + g * 8;
        return *reinterpret_cast<const bf16x8*>(&At[buf][row * 256 + (kloc ^ (r16 << 3))]);
    };
    auto loadB = [&](bf16x8 (&bb)[NT], int ss, int s) {
        int k = kq + ss * 256 + wave * 64 + s * 32 + g * 8;
        #pragma unroll
        for (int n = 0; n < NT; ++n)
            bb[n] = *reinterpret_cast<const bf16x8*>(Ht + (size_t)(n * 16 + r16) * LN + k);
    };

    stage_load(0);
    stage_write(0);
    __syncthreads();
    for (int ss = 0; ss < NSS; ++ss) {
        const int buf = ss & 1;
        if (ss + 1 < NSS) stage_load(ss + 1);
        #pragma unroll
        for (int s = 0; s < 2; ++s) {
            bf16x8 B[NT];
            loadB(B, ss, s);
            bf16x8 a0 = frag(buf, 0, s);
            bf16x8 a1 = frag(buf, 1, s);
            #pragma unroll
            for (int n = 0; n < NT; ++n) {
                acc[0][n] = __builtin_amdgcn_mfma_f32_16x16x32_bf16(a0, B[n], acc[0][n], 0, 0, 0);
                acc[1][n] = __builtin_amdgcn_mfma_f32_16x16x32_bf16(a1, B[n], acc[1][n], 0, 0, 0);
            }
        }
        __syncthreads();
        if (ss + 1 < NSS) stage_write(buf ^ 1);
        __syncthreads();
    }

    for (int w4 = 0; w4 < 4; ++w4) {
        if (wave == w4) {
            #pragma unroll
            for (int mt = 0; mt < 2; ++mt)
                #pragma unroll
                for (int n = 0; n < NT; ++n)
                    #pragma unroll
                    for (int q = 0; q < 4; ++q) {
                        int row = mt * 16 + g * 4 + q;
                        if (w4 == 0) red[row][n * 16 + r16]  = acc[mt][n][q];
                        else         red[row][n * 16 + r16] += acc[mt][n][q];
                    }
        }
        __syncthreads();
    }
    if (part) {
        float* dst = part + (size_t)blockIdx.y * (LN * DN);
        for (int t2 = tid; t2 < 32 * DN; t2 += 256) {
            int row = t2 / DN, col = t2 % DN;
            dst[(size_t)(m0 + row) * DN + col] = red[row][col];
        }
    } else {
        for (int t2 = tid; t2 < 32 * DN; t2 += 256) {
            int row = t2 / DN, col = t2 % DN;
            atomicAdd(&out[(size_t)(m0 + row) * DN + col], red[row][col]);
        }
    }
}

extern "C" void kernel_launch(void* const* d_in, const int* in_sizes, int n_in,
                              void* d_out, int out_size, void* d_ws, size_t ws_size,
                              hipStream_t stream) {
    const float* adj = (const float*)d_in[0];
    const float* h   = (const float*)d_in[1];
    float* out = (float*)d_out;
    char* ws = (char*)d_ws;

    unsigned short* Ht = (unsigned short*)ws;                      // 1.31 MB @ 0
    const size_t offPin  = 2u << 20;                               // h_in partials (4x)
    const size_t offPout = offPin + (size_t)KSPLIT * LN * DN * 4;  // h_out partials (8x)
    const size_t need    = offPout + (size_t)KS0 * LN * DN * 4;    // ~31.5 MB

    k_transpose<<<dim3(64, 5), 256, 0, stream>>>(h, Ht);

    if (ws_size >= need) {
        float* pIn  = (float*)(ws + offPin);
        float* pOut = (float*)(ws + offPout);
        k_gemm_a<<<dim3(64, KS0), 256, 0, stream>>>(adj, Ht, pOut);                // h_out
        k_gemm<1><<<dim3(128, KSPLIT), 256, 0, stream>>>(adj, Ht, pIn, nullptr);   // h_in
        const int n4 = (LN * DN) / 4;
        k_reduce<<<(n4 + 255) / 256, 256, 0, stream>>>(pIn, pOut, out, n4);
    } else {
        const int n4 = out_size / 4;
        k_zero<<<(n4 + 255) / 256, 256, 0, stream>>>((f32x4*)out, n4);
        k_gemm<0><<<dim3(128, KSPLIT), 256, 0, stream>>>(adj, Ht, nullptr, out + (size_t)LN * DN);
        k_gemm<1><<<dim3(128, KSPLIT), 256, 0, stream>>>(adj, Ht, nullptr, out);
    }
}